// Round 8
// baseline (441.197 us; speedup 1.0000x reference)
//
#include <hip/hip_runtime.h>
#include <hip/hip_bf16.h>
#include <cstdint>
#include <cstddef>

#define NN 100000
#define NE 1600000
#define TAU 0.3f

typedef __attribute__((ext_vector_type(8))) short bf16x8;
typedef __attribute__((ext_vector_type(4))) float f32x4;
typedef __attribute__((ext_vector_type(4))) uint u32x4;

#define NTL(p) __builtin_nontemporal_load(p)

static __device__ __forceinline__ float b2f_hi(uint w) {
  return __uint_as_float(w & 0xffff0000u);
}
static __device__ __forceinline__ float b2f_lo(uint w) {
  return __uint_as_float(w << 16);
}
static __device__ __forceinline__ ushort f2b(float f) {
  uint x = __float_as_uint(f);
  return (ushort)((x + 0x7fffu + ((x >> 16) & 1u)) >> 16);
}
// sign-extended byte k of word w -> float
static __device__ __forceinline__ float i8f(uint w, int k) {
  return (float)((int)(w << (24 - 8 * k)) >> 24);
}

// ------- K1: hist (blocks 0..6249) + conv_h (6250..12499) + prep (12500..12755) -------
__global__ __launch_bounds__(256) void setup_hist(
    const float* __restrict__ h, ushort* __restrict__ A,
    const float* __restrict__ Wq, const float* __restrict__ Wk, const float* __restrict__ Wm,
    const float* __restrict__ bq, const float* __restrict__ bk, const float* __restrict__ bm,
    const float* __restrict__ Wout,
    ushort* __restrict__ BTproj, ushort* __restrict__ BTout, float* __restrict__ bvec,
    const int* __restrict__ dst, int* __restrict__ counts) {
  int b = blockIdx.x;
  if (b < 6250) {                       // histogram over dst
    int e = b * 256 + threadIdx.x;
    if (e < NE) atomicAdd(&counts[NTL(&dst[e])], 1);
    return;
  }
  if (b < 12500) {                      // h f32 -> bf16
    int i = (b - 6250) * 256 + threadIdx.x;
    const f32x4* hv = (const f32x4*)h + (size_t)i * 2;
    f32x4 a = NTL(hv);
    f32x4 c = NTL(hv + 1);
    u32x4 o;
    o[0] = (uint)f2b(a[0]) | ((uint)f2b(a[1]) << 16);
    o[1] = (uint)f2b(a[2]) | ((uint)f2b(a[3]) << 16);
    o[2] = (uint)f2b(c[0]) | ((uint)f2b(c[1]) << 16);
    o[3] = (uint)f2b(c[2]) | ((uint)f2b(c[3]) << 16);
    __builtin_nontemporal_store(o, (u32x4*)A + i);
    return;
  }
  int id = (b - 12500) * 256 + threadIdx.x;   // weight prep, 65536 threads
  if (id < 384 * 128) {
    int j = id >> 7, k = id & 127;
    int w = j >> 7, r = j & 127, hh = r >> 5, d = r & 31;
    const float* W = (w == 0) ? Wq : (w == 1) ? Wk : Wm;
    BTproj[id] = f2b(W[hh * 4096 + k * 32 + d]);
    if (k == 0) {
      const float* bb = (w == 0) ? bq : (w == 1) ? bk : bm;
      bvec[j] = bb[hh * 32 + d];
    }
  } else {
    int id2 = id - 384 * 128;                // 16384
    int c = id2 >> 7, k = id2 & 127;
    BTout[id2] = f2b(Wout[k * 128 + c]);
  }
}

// ---------------- MFMA GEMM: C[M][NCB*128] = A[M][128] * BT^T + bias ----------------
// A staged in LDS once; col-blocks looped internally (B re-staged from L2).
template <int NCB, int RELU, int OUTBF>
__global__ __launch_bounds__(256) void mfma_gemm(
    const ushort* __restrict__ A, const ushort* __restrict__ BT,
    const float* __restrict__ bias, void* __restrict__ Cp, int M, int ncols) {
  __shared__ ushort As[128 * 128];
  __shared__ ushort Bs[128 * 128];

  int t = threadIdx.x;
  int rowBase = blockIdx.x * 128;

  // stage A tile once
#pragma unroll
  for (int i = 0; i < 8; i++) {
    int flat = t + i * 256;
    int row = flat >> 4;
    int kb = (flat & 15) * 16;
    int soff = kb ^ ((row & 7) << 4);
    int ar = rowBase + row; if (ar >= M) ar = M - 1;
    __builtin_amdgcn_global_load_lds(
        (const __attribute__((address_space(1))) uint32_t*)((const char*)A + (size_t)ar * 256 + soff),
        (__attribute__((address_space(3))) uint32_t*)((char*)As + row * 256 + kb), 16, 0, 0);
  }

  int wv = t >> 6, L = t & 63;
  int wrow = (wv >> 1) * 64, wcol = (wv & 1) * 64;
  int lr = L & 15;
  int lk = (L >> 4) * 16;
  int rquad = (L >> 4) * 4;

  for (int cb = 0; cb < NCB; cb++) {
    if (cb) __syncthreads();            // protect Bs overwrite
    int colBase = cb * 128;
#pragma unroll
    for (int i = 0; i < 8; i++) {
      int flat = t + i * 256;
      int row = flat >> 4;
      int kb = (flat & 15) * 16;
      int soff = kb ^ ((row & 7) << 4);
      __builtin_amdgcn_global_load_lds(
          (const __attribute__((address_space(1))) uint32_t*)((const char*)BT + (size_t)(colBase + row) * 256 + soff),
          (__attribute__((address_space(3))) uint32_t*)((char*)Bs + row * 256 + kb), 16, 0, 0);
    }
    __syncthreads();

    f32x4 acc[4][4] = {};
#pragma unroll
    for (int ks = 0; ks < 4; ks++) {
      bf16x8 a[4], bb[4];
#pragma unroll
      for (int i = 0; i < 4; i++) {
        int row = wrow + i * 16 + lr;
        a[i] = *(const bf16x8*)((const char*)As + row * 256 + ((ks * 64 + lk) ^ ((row & 7) << 4)));
        int col = wcol + i * 16 + lr;
        bb[i] = *(const bf16x8*)((const char*)Bs + col * 256 + ((ks * 64 + lk) ^ ((col & 7) << 4)));
      }
#pragma unroll
      for (int i = 0; i < 4; i++)
#pragma unroll
        for (int j = 0; j < 4; j++)
          acc[i][j] = __builtin_amdgcn_mfma_f32_16x16x32_bf16(a[i], bb[j], acc[i][j], 0, 0, 0);
    }

#pragma unroll
    for (int j = 0; j < 4; j++) {
      int col = colBase + wcol + j * 16 + lr;
      float bs = bias[col];
#pragma unroll
      for (int i = 0; i < 4; i++) {
        int row0 = rowBase + wrow + i * 16 + rquad;
#pragma unroll
        for (int r = 0; r < 4; r++) {
          int row = row0 + r;
          if (row >= M) continue;
          float v = acc[i][j][r] + bs;
          if (RELU) v = fmaxf(v, 0.f);
          if (OUTBF) __builtin_nontemporal_store(f2b(v), (ushort*)Cp + (size_t)row * ncols + col);
          else       __builtin_nontemporal_store(v, (float*)Cp + (size_t)row * ncols + col);
        }
      }
    }
  }
}

// ---------------- CSR scans ----------------
__global__ __launch_bounds__(256) void scan_a(const int* __restrict__ counts,
                                              int* __restrict__ offsets,
                                              int* __restrict__ blockSums, int n) {
  __shared__ int lds[256];
  int b = blockIdx.x, t = threadIdx.x;
  int base = b * 1024 + t * 4;
  int4 v = make_int4(0, 0, 0, 0);
  if (base < n) v = *(const int4*)&counts[base];
  int s1 = v.x + v.y, s2 = s1 + v.z, s3 = s2 + v.w;
  lds[t] = s3;
  __syncthreads();
  for (int dd = 1; dd < 256; dd <<= 1) {
    int x = (t >= dd) ? lds[t - dd] : 0;
    __syncthreads();
    lds[t] += x;
    __syncthreads();
  }
  int excl = (t > 0) ? lds[t - 1] : 0;
  if (base < n) {
    int4 o = make_int4(excl, excl + v.x, excl + s1, excl + s2);
    *(int4*)&offsets[base] = o;
  }
  if (t == 255) blockSums[b] = lds[255];
}

__global__ __launch_bounds__(128) void scan_b(int* __restrict__ blockSums, int nb) {
  __shared__ int lds[128];
  int t = threadIdx.x;
  lds[t] = (t < nb) ? blockSums[t] : 0;
  __syncthreads();
  for (int dd = 1; dd < 128; dd <<= 1) {
    int x = (t >= dd) ? lds[t - dd] : 0;
    __syncthreads();
    lds[t] += x;
    __syncthreads();
  }
  if (t < nb) blockSums[t] = (t > 0) ? lds[t - 1] : 0;
}

__global__ __launch_bounds__(256) void scan_c(int* __restrict__ offsets,
                                              const int* __restrict__ blockSums,
                                              int* __restrict__ cursor, int n) {
  int i = blockIdx.x * 256 + threadIdx.x;
  if (i < n) {
    int v = offsets[i] + blockSums[i >> 10];
    offsets[i] = v;
    cursor[i] = v;
  }
  if (i == 0) offsets[n] = NE;
}

// ------- K6: scatter (blocks 0..3127, XCD-partitioned) + bf16->int8 quant (3128..9377) -------
// Streaming reads are non-temporal so the partition's dirty CSR lines stay in its L2.
#define SC_CHUNK 4096
__global__ __launch_bounds__(256) void scatter_conv(
    const int* __restrict__ src, const int* __restrict__ dst,
    int* __restrict__ cursor, int* __restrict__ csr_src,
    const ushort* __restrict__ Zbf, char* __restrict__ Zkm,
    float2* __restrict__ scales) {
  int b = blockIdx.x;
  if (b < 3128) {
    int part = b & 7;
    int base = (b >> 3) * SC_CHUNK + threadIdx.x;
#pragma unroll
    for (int i = 0; i < SC_CHUNK / 256; i++) {
      int e = base + i * 256;
      if (e < NE) {
        int d = NTL(&dst[e]);
        if ((d >> 14) == part) {
          int pos = atomicAdd(&cursor[d], 1);
          csr_src[pos] = NTL(&src[e]);
        }
      }
    }
    return;
  }
  int g = (b - 3128) * 256 + threadIdx.x;   // 1.6M threads = 100K rows x 16 units
  int row = g >> 4, u = g & 15;
  const ushort* zr = Zbf + (size_t)row * 384;
  u32x4 kk = NTL((const u32x4*)(zr + 128 + u * 8));
  u32x4 mm = NTL((const u32x4*)(zr + 256 + u * 8));
  float kf[8] = {b2f_lo(kk[0]), b2f_hi(kk[0]), b2f_lo(kk[1]), b2f_hi(kk[1]),
                 b2f_lo(kk[2]), b2f_hi(kk[2]), b2f_lo(kk[3]), b2f_hi(kk[3])};
  float mf[8] = {b2f_lo(mm[0]), b2f_hi(mm[0]), b2f_lo(mm[1]), b2f_hi(mm[1]),
                 b2f_lo(mm[2]), b2f_hi(mm[2]), b2f_lo(mm[3]), b2f_hi(mm[3])};
  float mk = 0.f, mx = 0.f;
#pragma unroll
  for (int i = 0; i < 8; i++) { mk = fmaxf(mk, fabsf(kf[i])); mx = fmaxf(mx, fabsf(mf[i])); }
#pragma unroll
  for (int d = 1; d < 16; d <<= 1) {
    mk = fmaxf(mk, __shfl_xor(mk, d));
    mx = fmaxf(mx, __shfl_xor(mx, d));
  }
  mk = fmaxf(mk, 1e-20f); mx = fmaxf(mx, 1e-20f);
  float qk = 127.0f / mk, qm = 127.0f / mx;
  int q[16];
#pragma unroll
  for (int i = 0; i < 8; i++) {
    q[i] = __float2int_rn(kf[i] * qk) & 0xff;
    q[8 + i] = __float2int_rn(mf[i] * qm) & 0xff;
  }
  u32x4 o;
  o[0] = (uint)(q[0] | (q[1] << 8) | (q[2] << 16) | (q[3] << 24));
  o[1] = (uint)(q[4] | (q[5] << 8) | (q[6] << 16) | (q[7] << 24));
  o[2] = (uint)(q[8] | (q[9] << 8) | (q[10] << 16) | (q[11] << 24));
  o[3] = (uint)(q[12] | (q[13] << 8) | (q[14] << 16) | (q[15] << 24));
  *(u32x4*)(Zkm + (size_t)row * 256 + u * 16) = o;
  if (u == 0) scales[row] = make_float2(mk * (1.0f / 127.0f), mx * (1.0f / 127.0f));
}

// ---------------- fused attention + aggregation, int8 gathers, 4 edges/wave ----------------
// wave per node; lane L: quarter qt=L>>4 handles edge p+4g+qt; l=L&15 covers dims 8l..8l+7.
// 16-edge unroll: 4 gathers + 4 scale loads in flight per lane.
__global__ __launch_bounds__(256) void aggregate_q(
    const char* __restrict__ Zkm, const ushort* __restrict__ Zbf,
    const float2* __restrict__ scales,
    const int* __restrict__ offsets, const int* __restrict__ csr_src,
    ushort* __restrict__ aggbf) {
  int wv = threadIdx.x >> 6, L = threadIdx.x & 63;
  int n = blockIdx.x * 4 + wv;
  if (n >= NN) return;
  int qt = L >> 4, l = L & 15;
  int lb = l << 4;                         // byte offset within 256B row

  u32x4 qw = NTL((const u32x4*)((const char*)Zbf + (size_t)n * 768 + lb));  // zq dims 8l..8l+7
  float q0 = b2f_lo(qw[0]), q1 = b2f_hi(qw[0]), q2 = b2f_lo(qw[1]), q3 = b2f_hi(qw[1]);
  float q4 = b2f_lo(qw[2]), q5 = b2f_hi(qw[2]), q6 = b2f_lo(qw[3]), q7 = b2f_hi(qw[3]);

  int start = offsets[n], end = offsets[n + 1];
  float den = 0.f;
  float a0 = 0.f, a1 = 0.f, a2 = 0.f, a3 = 0.f, a4 = 0.f, a5 = 0.f, a6 = 0.f, a7 = 0.f;
  int p = start;

  for (; p + 16 <= end; p += 16) {
    int s[4];
#pragma unroll
    for (int g = 0; g < 4; g++) s[g] = NTL(&csr_src[p + 4 * g + qt]);
    u32x4 v[4];
#pragma unroll
    for (int g = 0; g < 4; g++) v[g] = *(const u32x4*)(Zkm + ((size_t)s[g] << 8) + lb);
    float2 sc[4];
#pragma unroll
    for (int g = 0; g < 4; g++) sc[g] = scales[s[g]];

    float pd[4];
#pragma unroll
    for (int g = 0; g < 4; g++) {
      float t0 = i8f(v[g][0], 0) * q0;
      t0 = fmaf(i8f(v[g][0], 1), q1, t0); t0 = fmaf(i8f(v[g][0], 2), q2, t0);
      t0 = fmaf(i8f(v[g][0], 3), q3, t0); t0 = fmaf(i8f(v[g][1], 0), q4, t0);
      t0 = fmaf(i8f(v[g][1], 1), q5, t0); t0 = fmaf(i8f(v[g][1], 2), q6, t0);
      t0 = fmaf(i8f(v[g][1], 3), q7, t0);
      pd[g] = t0;
    }
#pragma unroll
    for (int g = 0; g < 4; g++) pd[g] += __shfl_xor(pd[g], 1);
#pragma unroll
    for (int g = 0; g < 4; g++) pd[g] += __shfl_xor(pd[g], 2);
#pragma unroll
    for (int g = 0; g < 4; g++) {
      float w = __expf(TAU * sc[g].x * pd[g]);
      den += w;
      float wm = w * sc[g].y;
      a0 = fmaf(i8f(v[g][2], 0), wm, a0); a1 = fmaf(i8f(v[g][2], 1), wm, a1);
      a2 = fmaf(i8f(v[g][2], 2), wm, a2); a3 = fmaf(i8f(v[g][2], 3), wm, a3);
      a4 = fmaf(i8f(v[g][3], 0), wm, a4); a5 = fmaf(i8f(v[g][3], 1), wm, a5);
      a6 = fmaf(i8f(v[g][3], 2), wm, a6); a7 = fmaf(i8f(v[g][3], 3), wm, a7);
    }
  }

  for (; p < end; p += 4) {               // masked tail, whole wave stays
    int e = p + qt;
    int idx = (e < end) ? e : (end - 1);
    int s0 = NTL(&csr_src[idx]);
    u32x4 v = *(const u32x4*)(Zkm + ((size_t)s0 << 8) + lb);
    float2 sc = scales[s0];
    float pd = i8f(v[0], 0) * q0;
    pd = fmaf(i8f(v[0], 1), q1, pd); pd = fmaf(i8f(v[0], 2), q2, pd);
    pd = fmaf(i8f(v[0], 3), q3, pd); pd = fmaf(i8f(v[1], 0), q4, pd);
    pd = fmaf(i8f(v[1], 1), q5, pd); pd = fmaf(i8f(v[1], 2), q6, pd);
    pd = fmaf(i8f(v[1], 3), q7, pd);
    pd += __shfl_xor(pd, 1);
    pd += __shfl_xor(pd, 2);
    float w = (e < end) ? __expf(TAU * sc.x * pd) : 0.f;
    den += w;
    float wm = w * sc.y;
    a0 = fmaf(i8f(v[2], 0), wm, a0); a1 = fmaf(i8f(v[2], 1), wm, a1);
    a2 = fmaf(i8f(v[2], 2), wm, a2); a3 = fmaf(i8f(v[2], 3), wm, a3);
    a4 = fmaf(i8f(v[3], 0), wm, a4); a5 = fmaf(i8f(v[3], 1), wm, a5);
    a6 = fmaf(i8f(v[3], 2), wm, a6); a7 = fmaf(i8f(v[3], 3), wm, a7);
  }

  // combine the four quarters (same l -> same dims/head)
  den += __shfl_xor(den, 16); den += __shfl_xor(den, 32);
  a0 += __shfl_xor(a0, 16); a0 += __shfl_xor(a0, 32);
  a1 += __shfl_xor(a1, 16); a1 += __shfl_xor(a1, 32);
  a2 += __shfl_xor(a2, 16); a2 += __shfl_xor(a2, 32);
  a3 += __shfl_xor(a3, 16); a3 += __shfl_xor(a3, 32);
  a4 += __shfl_xor(a4, 16); a4 += __shfl_xor(a4, 32);
  a5 += __shfl_xor(a5, 16); a5 += __shfl_xor(a5, 32);
  a6 += __shfl_xor(a6, 16); a6 += __shfl_xor(a6, 32);
  a7 += __shfl_xor(a7, 16); a7 += __shfl_xor(a7, 32);

  float inv = (den > 0.f) ? 1.0f / den : 0.f;
  if (qt == 0) {
    u32x4 o;
    o[0] = (uint)f2b(a0 * inv) | ((uint)f2b(a1 * inv) << 16);
    o[1] = (uint)f2b(a2 * inv) | ((uint)f2b(a3 * inv) << 16);
    o[2] = (uint)f2b(a4 * inv) | ((uint)f2b(a5 * inv) << 16);
    o[3] = (uint)f2b(a6 * inv) | ((uint)f2b(a7 * inv) << 16);
    __builtin_nontemporal_store(o, (u32x4*)((char*)aggbf + (size_t)n * 256 + lb));
  }
}

// ---------------- launch ----------------
extern "C" void kernel_launch(void* const* d_in, const int* in_sizes, int n_in,
                              void* d_out, int out_size, void* d_ws, size_t ws_size,
                              hipStream_t stream) {
  const float* h    = (const float*)d_in[0];
  const int*   src  = (const int*)d_in[1];
  const int*   dst  = (const int*)d_in[2];
  const float* Wq   = (const float*)d_in[3];
  const float* bq   = (const float*)d_in[4];
  const float* Wk   = (const float*)d_in[5];
  const float* bk   = (const float*)d_in[6];
  const float* Wm   = (const float*)d_in[7];
  const float* bm   = (const float*)d_in[8];
  const float* Wout = (const float*)d_in[9];
  const float* bout = (const float*)d_in[10];
  float* out = (float*)d_out;

  char* base = (char*)d_ws;
  ushort* Abf    = (ushort*)base;                         // NN*128 bf16 (reused as Zkm)
  char*   Zkm    = base;                                  // NN*256B int8, overlaps Abf
  ushort* Zbf    = (ushort*)(base + 25600000);            // NN*384 bf16
  ushort* aggbf  = (ushort*)(base + 102400000);           // NN*128 bf16
  float2* scales = (float2*)(base + 128000000);           // NN float2 (800000 B)
  ushort* BTproj = (ushort*)(base + 128800000);           // 98304 B
  ushort* BTout  = (ushort*)(base + 128898304);           // 32768 B
  float*  bvec   = (float*)(base + 128931072);            // pad to 2048 B
  int* counts    = (int*)(base + 128933120);              // 400000 B
  int* offsets   = (int*)(base + 129333120);              // (NN+2)*4
  int* cursor    = (int*)(base + 129733128);              // 400000 B
  int* blockSums = (int*)(base + 130133128);              // 512 B
  int* csr_src   = (int*)(base + 130133640);              // NE*4

  hipMemsetAsync(counts, 0, (size_t)NN * sizeof(int), stream);

  setup_hist<<<12756, 256, 0, stream>>>(h, Abf, Wq, Wk, Wm, bq, bk, bm, Wout,
                                        BTproj, BTout, bvec, dst, counts);
  scan_a<<<98, 256, 0, stream>>>(counts, offsets, blockSums, NN);
  scan_b<<<1, 128, 0, stream>>>(blockSums, 98);
  scan_c<<<391, 256, 0, stream>>>(offsets, blockSums, cursor, NN);

  mfma_gemm<3, 0, 1><<<782, 256, 0, stream>>>(Abf, BTproj, bvec, Zbf, NN, 384);

  scatter_conv<<<9378, 256, 0, stream>>>(src, dst, cursor, csr_src, Zbf, Zkm, scales);

  aggregate_q<<<25000, 256, 0, stream>>>(Zkm, Zbf, scales, offsets, csr_src, aggbf);

  mfma_gemm<1, 1, 0><<<782, 256, 0, stream>>>(aggbf, BTout, bout, out, NN, 128);
}

// Round 9
// 391.132 us; speedup vs baseline: 1.1280x; 1.1280x over previous
//
#include <hip/hip_runtime.h>
#include <hip/hip_bf16.h>
#include <cstdint>
#include <cstddef>

#define NN 100000
#define NE 1600000
#define TAU 0.3f

typedef __attribute__((ext_vector_type(8))) short bf16x8;
typedef __attribute__((ext_vector_type(4))) float f32x4;
typedef __attribute__((ext_vector_type(4))) uint u32x4;

#define NTL(p) __builtin_nontemporal_load(p)

static __device__ __forceinline__ float b2f_hi(uint w) {
  return __uint_as_float(w & 0xffff0000u);
}
static __device__ __forceinline__ float b2f_lo(uint w) {
  return __uint_as_float(w << 16);
}
static __device__ __forceinline__ ushort f2b(float f) {
  uint x = __float_as_uint(f);
  return (ushort)((x + 0x7fffu + ((x >> 16) & 1u)) >> 16);
}
// sign-extended byte k of word w -> float
static __device__ __forceinline__ float i8f(uint w, int k) {
  return (float)((int)(w << (24 - 8 * k)) >> 24);
}

// ------- K1: hist (blocks 0..6249) + conv_h (6250..12499) + prep (12500..12755) -------
__global__ __launch_bounds__(256) void setup_hist(
    const float* __restrict__ h, ushort* __restrict__ A,
    const float* __restrict__ Wq, const float* __restrict__ Wk, const float* __restrict__ Wm,
    const float* __restrict__ bq, const float* __restrict__ bk, const float* __restrict__ bm,
    const float* __restrict__ Wout,
    ushort* __restrict__ BTproj, ushort* __restrict__ BTout, float* __restrict__ bvec,
    const int* __restrict__ dst, int* __restrict__ counts) {
  int b = blockIdx.x;
  if (b < 6250) {                       // histogram over dst
    int e = b * 256 + threadIdx.x;
    if (e < NE) atomicAdd(&counts[NTL(&dst[e])], 1);
    return;
  }
  if (b < 12500) {                      // h f32 -> bf16
    int i = (b - 6250) * 256 + threadIdx.x;
    const f32x4* hv = (const f32x4*)h + (size_t)i * 2;
    f32x4 a = NTL(hv);
    f32x4 c = NTL(hv + 1);
    u32x4 o;
    o[0] = (uint)f2b(a[0]) | ((uint)f2b(a[1]) << 16);
    o[1] = (uint)f2b(a[2]) | ((uint)f2b(a[3]) << 16);
    o[2] = (uint)f2b(c[0]) | ((uint)f2b(c[1]) << 16);
    o[3] = (uint)f2b(c[2]) | ((uint)f2b(c[3]) << 16);
    *((u32x4*)A + i) = o;
    return;
  }
  int id = (b - 12500) * 256 + threadIdx.x;   // weight prep, 65536 threads
  if (id < 384 * 128) {
    int j = id >> 7, k = id & 127;
    int w = j >> 7, r = j & 127, hh = r >> 5, d = r & 31;
    const float* W = (w == 0) ? Wq : (w == 1) ? Wk : Wm;
    BTproj[id] = f2b(W[hh * 4096 + k * 32 + d]);
    if (k == 0) {
      const float* bb = (w == 0) ? bq : (w == 1) ? bk : bm;
      bvec[j] = bb[hh * 32 + d];
    }
  } else {
    int id2 = id - 384 * 128;                // 16384
    int c = id2 >> 7, k = id2 & 127;
    BTout[id2] = f2b(Wout[k * 128 + c]);
  }
}

// ---------------- MFMA GEMM: C[M][ncols] = A[M][128] * BT^T + bias ----------------
// Round-7 known-good form: one 128x128 tile per block, plain stores.
template <int RELU, int OUTBF>
__global__ __launch_bounds__(256) void mfma_gemm(
    const ushort* __restrict__ A, const ushort* __restrict__ BT,
    const float* __restrict__ bias, void* __restrict__ Cp, int M, int ncols) {
  __shared__ ushort As[128 * 128];
  __shared__ ushort Bs[128 * 128];

  int t = threadIdx.x;
  int rowBase = blockIdx.x * 128, colBase = blockIdx.y * 128;

#pragma unroll
  for (int i = 0; i < 8; i++) {
    int flat = t + i * 256;
    int row = flat >> 4;
    int kb = (flat & 15) * 16;
    int soff = kb ^ ((row & 7) << 4);
    int ar = rowBase + row; if (ar >= M) ar = M - 1;
    __builtin_amdgcn_global_load_lds(
        (const __attribute__((address_space(1))) uint32_t*)((const char*)A + (size_t)ar * 256 + soff),
        (__attribute__((address_space(3))) uint32_t*)((char*)As + row * 256 + kb), 16, 0, 0);
    __builtin_amdgcn_global_load_lds(
        (const __attribute__((address_space(1))) uint32_t*)((const char*)BT + (size_t)(colBase + row) * 256 + soff),
        (__attribute__((address_space(3))) uint32_t*)((char*)Bs + row * 256 + kb), 16, 0, 0);
  }
  __syncthreads();

  int wv = t >> 6, L = t & 63;
  int wrow = (wv >> 1) * 64, wcol = (wv & 1) * 64;
  int lr = L & 15;
  int lk = (L >> 4) * 16;
  f32x4 acc[4][4] = {};

#pragma unroll
  for (int ks = 0; ks < 4; ks++) {
    bf16x8 a[4], b[4];
#pragma unroll
    for (int i = 0; i < 4; i++) {
      int row = wrow + i * 16 + lr;
      a[i] = *(const bf16x8*)((const char*)As + row * 256 + ((ks * 64 + lk) ^ ((row & 7) << 4)));
      int col = wcol + i * 16 + lr;
      b[i] = *(const bf16x8*)((const char*)Bs + col * 256 + ((ks * 64 + lk) ^ ((col & 7) << 4)));
    }
#pragma unroll
    for (int i = 0; i < 4; i++)
#pragma unroll
      for (int j = 0; j < 4; j++)
        acc[i][j] = __builtin_amdgcn_mfma_f32_16x16x32_bf16(a[i], b[j], acc[i][j], 0, 0, 0);
  }

  int rquad = (L >> 4) * 4;
#pragma unroll
  for (int j = 0; j < 4; j++) {
    int col = colBase + wcol + j * 16 + lr;
    float bs = bias[col];
#pragma unroll
    for (int i = 0; i < 4; i++) {
      int row0 = rowBase + wrow + i * 16 + rquad;
#pragma unroll
      for (int r = 0; r < 4; r++) {
        int row = row0 + r;
        if (row >= M) continue;
        float v = acc[i][j][r] + bs;
        if (RELU) v = fmaxf(v, 0.f);
        if (OUTBF) ((ushort*)Cp)[(size_t)row * ncols + col] = f2b(v);
        else       ((float*)Cp)[(size_t)row * ncols + col] = v;
      }
    }
  }
}

// ---------------- CSR scans ----------------
__global__ __launch_bounds__(256) void scan_a(const int* __restrict__ counts,
                                              int* __restrict__ offsets,
                                              int* __restrict__ blockSums, int n) {
  __shared__ int lds[256];
  int b = blockIdx.x, t = threadIdx.x;
  int base = b * 1024 + t * 4;
  int4 v = make_int4(0, 0, 0, 0);
  if (base < n) v = *(const int4*)&counts[base];
  int s1 = v.x + v.y, s2 = s1 + v.z, s3 = s2 + v.w;
  lds[t] = s3;
  __syncthreads();
  for (int dd = 1; dd < 256; dd <<= 1) {
    int x = (t >= dd) ? lds[t - dd] : 0;
    __syncthreads();
    lds[t] += x;
    __syncthreads();
  }
  int excl = (t > 0) ? lds[t - 1] : 0;
  if (base < n) {
    int4 o = make_int4(excl, excl + v.x, excl + s1, excl + s2);
    *(int4*)&offsets[base] = o;
  }
  if (t == 255) blockSums[b] = lds[255];
}

__global__ __launch_bounds__(128) void scan_b(int* __restrict__ blockSums, int nb) {
  __shared__ int lds[128];
  int t = threadIdx.x;
  lds[t] = (t < nb) ? blockSums[t] : 0;
  __syncthreads();
  for (int dd = 1; dd < 128; dd <<= 1) {
    int x = (t >= dd) ? lds[t - dd] : 0;
    __syncthreads();
    lds[t] += x;
    __syncthreads();
  }
  if (t < nb) blockSums[t] = (t > 0) ? lds[t - 1] : 0;
}

__global__ __launch_bounds__(256) void scan_c(int* __restrict__ offsets,
                                              const int* __restrict__ blockSums,
                                              int* __restrict__ cursor, int n) {
  int i = blockIdx.x * 256 + threadIdx.x;
  if (i < n) {
    int v = offsets[i] + blockSums[i >> 10];
    offsets[i] = v;
    cursor[i] = v;
  }
  if (i == 0) offsets[n] = NE;
}

// ------- K6: scatter (blocks 0..3127, XCD-partitioned) + bf16->int8 quant (3128..9377) -------
// NT loads on the streamed dst/src/Zbf so the partition's dirty CSR lines stay in its L2.
#define SC_CHUNK 4096
__global__ __launch_bounds__(256) void scatter_conv(
    const int* __restrict__ src, const int* __restrict__ dst,
    int* __restrict__ cursor, int* __restrict__ csr_src,
    const ushort* __restrict__ Zbf, char* __restrict__ Zkm,
    float2* __restrict__ scales) {
  int b = blockIdx.x;
  if (b < 3128) {
    int part = b & 7;
    int base = (b >> 3) * SC_CHUNK + threadIdx.x;
#pragma unroll
    for (int i = 0; i < SC_CHUNK / 256; i++) {
      int e = base + i * 256;
      if (e < NE) {
        int d = NTL(&dst[e]);
        if ((d >> 14) == part) {
          int pos = atomicAdd(&cursor[d], 1);
          csr_src[pos] = NTL(&src[e]);
        }
      }
    }
    return;
  }
  int g = (b - 3128) * 256 + threadIdx.x;   // 1.6M threads = 100K rows x 16 units
  int row = g >> 4, u = g & 15;
  const ushort* zr = Zbf + (size_t)row * 384;
  u32x4 kk = NTL((const u32x4*)(zr + 128 + u * 8));
  u32x4 mm = NTL((const u32x4*)(zr + 256 + u * 8));
  float kf[8] = {b2f_lo(kk[0]), b2f_hi(kk[0]), b2f_lo(kk[1]), b2f_hi(kk[1]),
                 b2f_lo(kk[2]), b2f_hi(kk[2]), b2f_lo(kk[3]), b2f_hi(kk[3])};
  float mf[8] = {b2f_lo(mm[0]), b2f_hi(mm[0]), b2f_lo(mm[1]), b2f_hi(mm[1]),
                 b2f_lo(mm[2]), b2f_hi(mm[2]), b2f_lo(mm[3]), b2f_hi(mm[3])};
  float mk = 0.f, mx = 0.f;
#pragma unroll
  for (int i = 0; i < 8; i++) { mk = fmaxf(mk, fabsf(kf[i])); mx = fmaxf(mx, fabsf(mf[i])); }
#pragma unroll
  for (int d = 1; d < 16; d <<= 1) {
    mk = fmaxf(mk, __shfl_xor(mk, d));
    mx = fmaxf(mx, __shfl_xor(mx, d));
  }
  mk = fmaxf(mk, 1e-20f); mx = fmaxf(mx, 1e-20f);
  float qk = 127.0f / mk, qm = 127.0f / mx;
  int q[16];
#pragma unroll
  for (int i = 0; i < 8; i++) {
    q[i] = __float2int_rn(kf[i] * qk) & 0xff;
    q[8 + i] = __float2int_rn(mf[i] * qm) & 0xff;
  }
  u32x4 o;
  o[0] = (uint)(q[0] | (q[1] << 8) | (q[2] << 16) | (q[3] << 24));
  o[1] = (uint)(q[4] | (q[5] << 8) | (q[6] << 16) | (q[7] << 24));
  o[2] = (uint)(q[8] | (q[9] << 8) | (q[10] << 16) | (q[11] << 24));
  o[3] = (uint)(q[12] | (q[13] << 8) | (q[14] << 16) | (q[15] << 24));
  *(u32x4*)(Zkm + (size_t)row * 256 + u * 16) = o;
  if (u == 0) scales[row] = make_float2(mk * (1.0f / 127.0f), mx * (1.0f / 127.0f));
}

// ---------------- fused attention + aggregation, int8 gathers, 16-edge unroll ----------------
// wave per node; lane L: quarter qt=L>>4 handles edge p+4g+qt; l=L&15 covers dims 8l..8l+7.
__global__ __launch_bounds__(256) void aggregate_q(
    const char* __restrict__ Zkm, const ushort* __restrict__ Zbf,
    const float2* __restrict__ scales,
    const int* __restrict__ offsets, const int* __restrict__ csr_src,
    ushort* __restrict__ aggbf) {
  int wv = threadIdx.x >> 6, L = threadIdx.x & 63;
  int n = blockIdx.x * 4 + wv;
  if (n >= NN) return;
  int qt = L >> 4, l = L & 15;
  int lb = l << 4;                         // byte offset within 256B row

  u32x4 qw = *(const u32x4*)((const char*)Zbf + (size_t)n * 768 + lb);  // zq dims 8l..8l+7
  float q0 = b2f_lo(qw[0]), q1 = b2f_hi(qw[0]), q2 = b2f_lo(qw[1]), q3 = b2f_hi(qw[1]);
  float q4 = b2f_lo(qw[2]), q5 = b2f_hi(qw[2]), q6 = b2f_lo(qw[3]), q7 = b2f_hi(qw[3]);

  int start = offsets[n], end = offsets[n + 1];
  float den = 0.f;
  float a0 = 0.f, a1 = 0.f, a2 = 0.f, a3 = 0.f, a4 = 0.f, a5 = 0.f, a6 = 0.f, a7 = 0.f;
  int p = start;

  for (; p + 16 <= end; p += 16) {
    int s[4];
#pragma unroll
    for (int g = 0; g < 4; g++) s[g] = NTL(&csr_src[p + 4 * g + qt]);
    u32x4 v[4];
#pragma unroll
    for (int g = 0; g < 4; g++) v[g] = *(const u32x4*)(Zkm + ((size_t)s[g] << 8) + lb);
    float2 sc[4];
#pragma unroll
    for (int g = 0; g < 4; g++) sc[g] = scales[s[g]];

    float pd[4];
#pragma unroll
    for (int g = 0; g < 4; g++) {
      float t0 = i8f(v[g][0], 0) * q0;
      t0 = fmaf(i8f(v[g][0], 1), q1, t0); t0 = fmaf(i8f(v[g][0], 2), q2, t0);
      t0 = fmaf(i8f(v[g][0], 3), q3, t0); t0 = fmaf(i8f(v[g][1], 0), q4, t0);
      t0 = fmaf(i8f(v[g][1], 1), q5, t0); t0 = fmaf(i8f(v[g][1], 2), q6, t0);
      t0 = fmaf(i8f(v[g][1], 3), q7, t0);
      pd[g] = t0;
    }
#pragma unroll
    for (int g = 0; g < 4; g++) pd[g] += __shfl_xor(pd[g], 1);
#pragma unroll
    for (int g = 0; g < 4; g++) pd[g] += __shfl_xor(pd[g], 2);
#pragma unroll
    for (int g = 0; g < 4; g++) {
      float w = __expf(TAU * sc[g].x * pd[g]);
      den += w;
      float wm = w * sc[g].y;
      a0 = fmaf(i8f(v[g][2], 0), wm, a0); a1 = fmaf(i8f(v[g][2], 1), wm, a1);
      a2 = fmaf(i8f(v[g][2], 2), wm, a2); a3 = fmaf(i8f(v[g][2], 3), wm, a3);
      a4 = fmaf(i8f(v[g][3], 0), wm, a4); a5 = fmaf(i8f(v[g][3], 1), wm, a5);
      a6 = fmaf(i8f(v[g][3], 2), wm, a6); a7 = fmaf(i8f(v[g][3], 3), wm, a7);
    }
  }

  for (; p < end; p += 4) {               // masked tail, whole wave stays
    int e = p + qt;
    int idx = (e < end) ? e : (end - 1);
    int s0 = NTL(&csr_src[idx]);
    u32x4 v = *(const u32x4*)(Zkm + ((size_t)s0 << 8) + lb);
    float2 sc = scales[s0];
    float pd = i8f(v[0], 0) * q0;
    pd = fmaf(i8f(v[0], 1), q1, pd); pd = fmaf(i8f(v[0], 2), q2, pd);
    pd = fmaf(i8f(v[0], 3), q3, pd); pd = fmaf(i8f(v[1], 0), q4, pd);
    pd = fmaf(i8f(v[1], 1), q5, pd); pd = fmaf(i8f(v[1], 2), q6, pd);
    pd = fmaf(i8f(v[1], 3), q7, pd);
    pd += __shfl_xor(pd, 1);
    pd += __shfl_xor(pd, 2);
    float w = (e < end) ? __expf(TAU * sc.x * pd) : 0.f;
    den += w;
    float wm = w * sc.y;
    a0 = fmaf(i8f(v[2], 0), wm, a0); a1 = fmaf(i8f(v[2], 1), wm, a1);
    a2 = fmaf(i8f(v[2], 2), wm, a2); a3 = fmaf(i8f(v[2], 3), wm, a3);
    a4 = fmaf(i8f(v[3], 0), wm, a4); a5 = fmaf(i8f(v[3], 1), wm, a5);
    a6 = fmaf(i8f(v[3], 2), wm, a6); a7 = fmaf(i8f(v[3], 3), wm, a7);
  }

  // combine the four quarters (same l -> same dims/head)
  den += __shfl_xor(den, 16); den += __shfl_xor(den, 32);
  a0 += __shfl_xor(a0, 16); a0 += __shfl_xor(a0, 32);
  a1 += __shfl_xor(a1, 16); a1 += __shfl_xor(a1, 32);
  a2 += __shfl_xor(a2, 16); a2 += __shfl_xor(a2, 32);
  a3 += __shfl_xor(a3, 16); a3 += __shfl_xor(a3, 32);
  a4 += __shfl_xor(a4, 16); a4 += __shfl_xor(a4, 32);
  a5 += __shfl_xor(a5, 16); a5 += __shfl_xor(a5, 32);
  a6 += __shfl_xor(a6, 16); a6 += __shfl_xor(a6, 32);
  a7 += __shfl_xor(a7, 16); a7 += __shfl_xor(a7, 32);

  float inv = (den > 0.f) ? 1.0f / den : 0.f;
  if (qt == 0) {
    u32x4 o;
    o[0] = (uint)f2b(a0 * inv) | ((uint)f2b(a1 * inv) << 16);
    o[1] = (uint)f2b(a2 * inv) | ((uint)f2b(a3 * inv) << 16);
    o[2] = (uint)f2b(a4 * inv) | ((uint)f2b(a5 * inv) << 16);
    o[3] = (uint)f2b(a6 * inv) | ((uint)f2b(a7 * inv) << 16);
    *(u32x4*)((char*)aggbf + (size_t)n * 256 + lb) = o;
  }
}

// ---------------- launch ----------------
extern "C" void kernel_launch(void* const* d_in, const int* in_sizes, int n_in,
                              void* d_out, int out_size, void* d_ws, size_t ws_size,
                              hipStream_t stream) {
  const float* h    = (const float*)d_in[0];
  const int*   src  = (const int*)d_in[1];
  const int*   dst  = (const int*)d_in[2];
  const float* Wq   = (const float*)d_in[3];
  const float* bq   = (const float*)d_in[4];
  const float* Wk   = (const float*)d_in[5];
  const float* bk   = (const float*)d_in[6];
  const float* Wm   = (const float*)d_in[7];
  const float* bm   = (const float*)d_in[8];
  const float* Wout = (const float*)d_in[9];
  const float* bout = (const float*)d_in[10];
  float* out = (float*)d_out;

  char* base = (char*)d_ws;
  ushort* Abf    = (ushort*)base;                         // NN*128 bf16 (reused as Zkm)
  char*   Zkm    = base;                                  // NN*256B int8, overlaps Abf
  ushort* Zbf    = (ushort*)(base + 25600000);            // NN*384 bf16
  ushort* aggbf  = (ushort*)(base + 102400000);           // NN*128 bf16
  float2* scales = (float2*)(base + 128000000);           // NN float2
  ushort* BTproj = (ushort*)(base + 128800000);           // 98304 B
  ushort* BTout  = (ushort*)(base + 128898304);           // 32768 B
  float*  bvec   = (float*)(base + 128931072);            // pad to 2048 B
  int* counts    = (int*)(base + 128933120);              // 400000 B
  int* offsets   = (int*)(base + 129333120);              // (NN+2)*4
  int* cursor    = (int*)(base + 129733128);              // 400000 B
  int* blockSums = (int*)(base + 130133128);              // 512 B
  int* csr_src   = (int*)(base + 130133640);              // NE*4

  hipMemsetAsync(counts, 0, (size_t)NN * sizeof(int), stream);

  setup_hist<<<12756, 256, 0, stream>>>(h, Abf, Wq, Wk, Wm, bq, bk, bm, Wout,
                                        BTproj, BTout, bvec, dst, counts);
  scan_a<<<98, 256, 0, stream>>>(counts, offsets, blockSums, NN);
  scan_b<<<1, 128, 0, stream>>>(blockSums, 98);
  scan_c<<<391, 256, 0, stream>>>(offsets, blockSums, cursor, NN);

  mfma_gemm<0, 1><<<dim3(782, 3), 256, 0, stream>>>(Abf, BTproj, bvec, Zbf, NN, 384);

  scatter_conv<<<9378, 256, 0, stream>>>(src, dst, cursor, csr_src, Zbf, Zkm, scales);

  aggregate_q<<<25000, 256, 0, stream>>>(Zkm, Zbf, scales, offsets, csr_src, aggbf);

  mfma_gemm<1, 0><<<dim3(782, 1), 256, 0, stream>>>(aggbf, BTout, bout, out, NN, 128);
}

// Round 10
// 342.116 us; speedup vs baseline: 1.2896x; 1.1433x over previous
//
#include <hip/hip_runtime.h>
#include <hip/hip_bf16.h>
#include <cstdint>
#include <cstddef>

#define NN 100000
#define NE 1600000
#define TAU 0.3f

typedef __attribute__((ext_vector_type(8))) short bf16x8;
typedef __attribute__((ext_vector_type(4))) float f32x4;

#define NTL(p) __builtin_nontemporal_load(p)

static __device__ __forceinline__ float b2f_hi(uint w) {
  return __uint_as_float(w & 0xffff0000u);
}
static __device__ __forceinline__ float b2f_lo(uint w) {
  return __uint_as_float(w << 16);
}
static __device__ __forceinline__ ushort f2b(float f) {
  uint x = __float_as_uint(f);
  return (ushort)((x + 0x7fffu + ((x >> 16) & 1u)) >> 16);
}
// sign-extended byte k of word w -> float
static __device__ __forceinline__ float i8f(uint w, int k) {
  return (float)((int)(w << (24 - 8 * k)) >> 24);
}

// ------- K1: hist (blocks 0..6249) + conv_h (6250..12499) + prep (12500..12755) -------
__global__ __launch_bounds__(256) void setup_hist(
    const float* __restrict__ h, ushort* __restrict__ A,
    const float* __restrict__ Wq, const float* __restrict__ Wk, const float* __restrict__ Wm,
    const float* __restrict__ bq, const float* __restrict__ bk, const float* __restrict__ bm,
    const float* __restrict__ Wout,
    ushort* __restrict__ BTproj, ushort* __restrict__ BTout, float* __restrict__ bvec,
    const int* __restrict__ dst, int* __restrict__ counts) {
  int b = blockIdx.x;
  if (b < 6250) {                       // histogram over dst
    int e = b * 256 + threadIdx.x;
    if (e < NE) atomicAdd(&counts[dst[e]], 1);
    return;
  }
  if (b < 12500) {                      // h f32 -> bf16
    int i = (b - 6250) * 256 + threadIdx.x;
    const float4* hv = (const float4*)h + (size_t)i * 2;
    float4 a = hv[0], c = hv[1];
    uint4 o;
    o.x = (uint)f2b(a.x) | ((uint)f2b(a.y) << 16);
    o.y = (uint)f2b(a.z) | ((uint)f2b(a.w) << 16);
    o.z = (uint)f2b(c.x) | ((uint)f2b(c.y) << 16);
    o.w = (uint)f2b(c.z) | ((uint)f2b(c.w) << 16);
    ((uint4*)A)[i] = o;
    return;
  }
  int id = (b - 12500) * 256 + threadIdx.x;   // weight prep, 65536 threads
  if (id < 384 * 128) {
    int j = id >> 7, k = id & 127;
    int w = j >> 7, r = j & 127, hh = r >> 5, d = r & 31;
    const float* W = (w == 0) ? Wq : (w == 1) ? Wk : Wm;
    BTproj[id] = f2b(W[hh * 4096 + k * 32 + d]);
    if (k == 0) {
      const float* bb = (w == 0) ? bq : (w == 1) ? bk : bm;
      bvec[j] = bb[hh * 32 + d];
    }
  } else {
    int id2 = id - 384 * 128;                // 16384
    int c = id2 >> 7, k = id2 & 127;
    BTout[id2] = f2b(Wout[k * 128 + c]);
  }
}

// ---------------- MFMA GEMM: C[M][ncols] = A[M][128] * BT^T + bias ----------------
template <int RELU, int OUTBF>
__global__ __launch_bounds__(256) void mfma_gemm(
    const ushort* __restrict__ A, const ushort* __restrict__ BT,
    const float* __restrict__ bias, void* __restrict__ Cp, int M, int ncols) {
  __shared__ ushort As[128 * 128];
  __shared__ ushort Bs[128 * 128];

  int t = threadIdx.x;
  int rowBase = blockIdx.x * 128, colBase = blockIdx.y * 128;

#pragma unroll
  for (int i = 0; i < 8; i++) {
    int flat = t + i * 256;
    int row = flat >> 4;
    int kb = (flat & 15) * 16;
    int soff = kb ^ ((row & 7) << 4);
    int ar = rowBase + row; if (ar >= M) ar = M - 1;
    __builtin_amdgcn_global_load_lds(
        (const __attribute__((address_space(1))) uint32_t*)((const char*)A + (size_t)ar * 256 + soff),
        (__attribute__((address_space(3))) uint32_t*)((char*)As + row * 256 + kb), 16, 0, 0);
    __builtin_amdgcn_global_load_lds(
        (const __attribute__((address_space(1))) uint32_t*)((const char*)BT + (size_t)(colBase + row) * 256 + soff),
        (__attribute__((address_space(3))) uint32_t*)((char*)Bs + row * 256 + kb), 16, 0, 0);
  }
  __syncthreads();

  int wv = t >> 6, L = t & 63;
  int wrow = (wv >> 1) * 64, wcol = (wv & 1) * 64;
  int lr = L & 15;
  int lk = (L >> 4) * 16;
  f32x4 acc[4][4] = {};

#pragma unroll
  for (int ks = 0; ks < 4; ks++) {
    bf16x8 a[4], b[4];
#pragma unroll
    for (int i = 0; i < 4; i++) {
      int row = wrow + i * 16 + lr;
      a[i] = *(const bf16x8*)((const char*)As + row * 256 + ((ks * 64 + lk) ^ ((row & 7) << 4)));
      int col = wcol + i * 16 + lr;
      b[i] = *(const bf16x8*)((const char*)Bs + col * 256 + ((ks * 64 + lk) ^ ((col & 7) << 4)));
    }
#pragma unroll
    for (int i = 0; i < 4; i++)
#pragma unroll
      for (int j = 0; j < 4; j++)
        acc[i][j] = __builtin_amdgcn_mfma_f32_16x16x32_bf16(a[i], b[j], acc[i][j], 0, 0, 0);
  }

  int rquad = (L >> 4) * 4;
#pragma unroll
  for (int j = 0; j < 4; j++) {
    int col = colBase + wcol + j * 16 + lr;
    float bs = bias[col];
#pragma unroll
    for (int i = 0; i < 4; i++) {
      int row0 = rowBase + wrow + i * 16 + rquad;
#pragma unroll
      for (int r = 0; r < 4; r++) {
        int row = row0 + r;
        if (row >= M) continue;
        float v = acc[i][j][r] + bs;
        if (RELU) v = fmaxf(v, 0.f);
        if (OUTBF) ((ushort*)Cp)[(size_t)row * ncols + col] = f2b(v);
        else       ((float*)Cp)[(size_t)row * ncols + col] = v;
      }
    }
  }
}

// ---------------- CSR scans ----------------
__global__ __launch_bounds__(256) void scan_a(const int* __restrict__ counts,
                                              int* __restrict__ offsets,
                                              int* __restrict__ blockSums, int n) {
  __shared__ int lds[256];
  int b = blockIdx.x, t = threadIdx.x;
  int base = b * 1024 + t * 4;
  int4 v = make_int4(0, 0, 0, 0);
  if (base < n) v = *(const int4*)&counts[base];
  int s1 = v.x + v.y, s2 = s1 + v.z, s3 = s2 + v.w;
  lds[t] = s3;
  __syncthreads();
  for (int dd = 1; dd < 256; dd <<= 1) {
    int x = (t >= dd) ? lds[t - dd] : 0;
    __syncthreads();
    lds[t] += x;
    __syncthreads();
  }
  int excl = (t > 0) ? lds[t - 1] : 0;
  if (base < n) {
    int4 o = make_int4(excl, excl + v.x, excl + s1, excl + s2);
    *(int4*)&offsets[base] = o;
  }
  if (t == 255) blockSums[b] = lds[255];
}

__global__ __launch_bounds__(128) void scan_b(int* __restrict__ blockSums, int nb) {
  __shared__ int lds[128];
  int t = threadIdx.x;
  lds[t] = (t < nb) ? blockSums[t] : 0;
  __syncthreads();
  for (int dd = 1; dd < 128; dd <<= 1) {
    int x = (t >= dd) ? lds[t - dd] : 0;
    __syncthreads();
    lds[t] += x;
    __syncthreads();
  }
  if (t < nb) blockSums[t] = (t > 0) ? lds[t - 1] : 0;
}

__global__ __launch_bounds__(256) void scan_c(int* __restrict__ offsets,
                                              const int* __restrict__ blockSums,
                                              int* __restrict__ cursor, int n) {
  int i = blockIdx.x * 256 + threadIdx.x;
  if (i < n) {
    int v = offsets[i] + blockSums[i >> 10];
    offsets[i] = v;
    cursor[i] = v;
  }
  if (i == 0) offsets[n] = NE;
}

// ------- K6: scatter (blocks 0..3127, XCD-partitioned) + bf16->int8 quant (3128..9377) -------
// ONLY delta vs round 7: NT loads on the dst/src streams in the scatter branch so the
// partition's dirty CSR lines are not evicted from its L2 by the streaming index reads.
#define SC_CHUNK 4096
__global__ __launch_bounds__(256) void scatter_conv(
    const int* __restrict__ src, const int* __restrict__ dst,
    int* __restrict__ cursor, int* __restrict__ csr_src,
    const ushort* __restrict__ Zbf, char* __restrict__ Zkm,
    float2* __restrict__ scales) {
  int b = blockIdx.x;
  if (b < 3128) {
    int part = b & 7;
    int base = (b >> 3) * SC_CHUNK + threadIdx.x;
#pragma unroll
    for (int i = 0; i < SC_CHUNK / 256; i++) {
      int e = base + i * 256;
      if (e < NE) {
        int d = NTL(&dst[e]);
        if ((d >> 14) == part) {
          int pos = atomicAdd(&cursor[d], 1);
          csr_src[pos] = NTL(&src[e]);
        }
      }
    }
    return;
  }
  int g = (b - 3128) * 256 + threadIdx.x;   // 1.6M threads = 100K rows x 16 units
  int row = g >> 4, u = g & 15;
  const ushort* zr = Zbf + (size_t)row * 384;
  uint4 kk = *(const uint4*)(zr + 128 + u * 8);
  uint4 mm = *(const uint4*)(zr + 256 + u * 8);
  float kf[8] = {b2f_lo(kk.x), b2f_hi(kk.x), b2f_lo(kk.y), b2f_hi(kk.y),
                 b2f_lo(kk.z), b2f_hi(kk.z), b2f_lo(kk.w), b2f_hi(kk.w)};
  float mf[8] = {b2f_lo(mm.x), b2f_hi(mm.x), b2f_lo(mm.y), b2f_hi(mm.y),
                 b2f_lo(mm.z), b2f_hi(mm.z), b2f_lo(mm.w), b2f_hi(mm.w)};
  float mk = 0.f, mx = 0.f;
#pragma unroll
  for (int i = 0; i < 8; i++) { mk = fmaxf(mk, fabsf(kf[i])); mx = fmaxf(mx, fabsf(mf[i])); }
#pragma unroll
  for (int d = 1; d < 16; d <<= 1) {
    mk = fmaxf(mk, __shfl_xor(mk, d));
    mx = fmaxf(mx, __shfl_xor(mx, d));
  }
  mk = fmaxf(mk, 1e-20f); mx = fmaxf(mx, 1e-20f);
  float qk = 127.0f / mk, qm = 127.0f / mx;
  int q[16];
#pragma unroll
  for (int i = 0; i < 8; i++) {
    q[i] = __float2int_rn(kf[i] * qk) & 0xff;
    q[8 + i] = __float2int_rn(mf[i] * qm) & 0xff;
  }
  uint4 o;
  o.x = (uint)(q[0] | (q[1] << 8) | (q[2] << 16) | (q[3] << 24));
  o.y = (uint)(q[4] | (q[5] << 8) | (q[6] << 16) | (q[7] << 24));
  o.z = (uint)(q[8] | (q[9] << 8) | (q[10] << 16) | (q[11] << 24));
  o.w = (uint)(q[12] | (q[13] << 8) | (q[14] << 16) | (q[15] << 24));
  *(uint4*)(Zkm + (size_t)row * 256 + u * 16) = o;
  if (u == 0) scales[row] = make_float2(mk * (1.0f / 127.0f), mx * (1.0f / 127.0f));
}

// ---------------- fused attention + aggregation, int8 gathers, 4 edges/wave ----------------
// Round-7 known-good form: 8-edge main loop (2 gathers in flight), VGPR ~20, occ ~72%.
__global__ __launch_bounds__(256) void aggregate_q(
    const char* __restrict__ Zkm, const ushort* __restrict__ Zbf,
    const float2* __restrict__ scales,
    const int* __restrict__ offsets, const int* __restrict__ csr_src,
    ushort* __restrict__ aggbf) {
  int wv = threadIdx.x >> 6, L = threadIdx.x & 63;
  int n = blockIdx.x * 4 + wv;
  if (n >= NN) return;
  int qt = L >> 4, l = L & 15;
  int lb = l << 4;                         // byte offset within 256B row

  uint4 qw = *(const uint4*)((const char*)Zbf + (size_t)n * 768 + lb);  // zq dims 8l..8l+7
  float q0 = b2f_lo(qw.x), q1 = b2f_hi(qw.x), q2 = b2f_lo(qw.y), q3 = b2f_hi(qw.y);
  float q4 = b2f_lo(qw.z), q5 = b2f_hi(qw.z), q6 = b2f_lo(qw.w), q7 = b2f_hi(qw.w);

  int start = offsets[n], end = offsets[n + 1];
  float den = 0.f;
  float a0 = 0.f, a1 = 0.f, a2 = 0.f, a3 = 0.f, a4 = 0.f, a5 = 0.f, a6 = 0.f, a7 = 0.f;
  int p = start;

  for (; p + 8 <= end; p += 8) {
    int s0 = csr_src[p + qt];
    int s1 = csr_src[p + 4 + qt];
    uint4 v0 = *(const uint4*)(Zkm + ((size_t)s0 << 8) + lb);
    uint4 v1 = *(const uint4*)(Zkm + ((size_t)s1 << 8) + lb);
    float2 sc0 = scales[s0];
    float2 sc1 = scales[s1];

    float pd0 = i8f(v0.x, 0) * q0;
    pd0 = fmaf(i8f(v0.x, 1), q1, pd0); pd0 = fmaf(i8f(v0.x, 2), q2, pd0);
    pd0 = fmaf(i8f(v0.x, 3), q3, pd0); pd0 = fmaf(i8f(v0.y, 0), q4, pd0);
    pd0 = fmaf(i8f(v0.y, 1), q5, pd0); pd0 = fmaf(i8f(v0.y, 2), q6, pd0);
    pd0 = fmaf(i8f(v0.y, 3), q7, pd0);
    float pd1 = i8f(v1.x, 0) * q0;
    pd1 = fmaf(i8f(v1.x, 1), q1, pd1); pd1 = fmaf(i8f(v1.x, 2), q2, pd1);
    pd1 = fmaf(i8f(v1.x, 3), q3, pd1); pd1 = fmaf(i8f(v1.y, 0), q4, pd1);
    pd1 = fmaf(i8f(v1.y, 1), q5, pd1); pd1 = fmaf(i8f(v1.y, 2), q6, pd1);
    pd1 = fmaf(i8f(v1.y, 3), q7, pd1);

    pd0 += __shfl_xor(pd0, 1); pd1 += __shfl_xor(pd1, 1);
    pd0 += __shfl_xor(pd0, 2); pd1 += __shfl_xor(pd1, 2);
    float w0 = __expf(TAU * sc0.x * pd0);
    float w1 = __expf(TAU * sc1.x * pd1);
    den += w0 + w1;
    float wm0 = w0 * sc0.y, wm1 = w1 * sc1.y;

    a0 = fmaf(i8f(v0.z, 0), wm0, a0); a1 = fmaf(i8f(v0.z, 1), wm0, a1);
    a2 = fmaf(i8f(v0.z, 2), wm0, a2); a3 = fmaf(i8f(v0.z, 3), wm0, a3);
    a4 = fmaf(i8f(v0.w, 0), wm0, a4); a5 = fmaf(i8f(v0.w, 1), wm0, a5);
    a6 = fmaf(i8f(v0.w, 2), wm0, a6); a7 = fmaf(i8f(v0.w, 3), wm0, a7);
    a0 = fmaf(i8f(v1.z, 0), wm1, a0); a1 = fmaf(i8f(v1.z, 1), wm1, a1);
    a2 = fmaf(i8f(v1.z, 2), wm1, a2); a3 = fmaf(i8f(v1.z, 3), wm1, a3);
    a4 = fmaf(i8f(v1.w, 0), wm1, a4); a5 = fmaf(i8f(v1.w, 1), wm1, a5);
    a6 = fmaf(i8f(v1.w, 2), wm1, a6); a7 = fmaf(i8f(v1.w, 3), wm1, a7);
  }

  for (; p < end; p += 4) {               // masked tail, whole wave stays
    int e = p + qt;
    int idx = (e < end) ? e : (end - 1);
    int s0 = csr_src[idx];
    uint4 v = *(const uint4*)(Zkm + ((size_t)s0 << 8) + lb);
    float2 sc = scales[s0];
    float pd = i8f(v.x, 0) * q0;
    pd = fmaf(i8f(v.x, 1), q1, pd); pd = fmaf(i8f(v.x, 2), q2, pd);
    pd = fmaf(i8f(v.x, 3), q3, pd); pd = fmaf(i8f(v.y, 0), q4, pd);
    pd = fmaf(i8f(v.y, 1), q5, pd); pd = fmaf(i8f(v.y, 2), q6, pd);
    pd = fmaf(i8f(v.y, 3), q7, pd);
    pd += __shfl_xor(pd, 1);
    pd += __shfl_xor(pd, 2);
    float w = (e < end) ? __expf(TAU * sc.x * pd) : 0.f;
    den += w;
    float wm = w * sc.y;
    a0 = fmaf(i8f(v.z, 0), wm, a0); a1 = fmaf(i8f(v.z, 1), wm, a1);
    a2 = fmaf(i8f(v.z, 2), wm, a2); a3 = fmaf(i8f(v.z, 3), wm, a3);
    a4 = fmaf(i8f(v.w, 0), wm, a4); a5 = fmaf(i8f(v.w, 1), wm, a5);
    a6 = fmaf(i8f(v.w, 2), wm, a6); a7 = fmaf(i8f(v.w, 3), wm, a7);
  }

  // combine the four quarters (same l -> same dims/head)
  den += __shfl_xor(den, 16); den += __shfl_xor(den, 32);
  a0 += __shfl_xor(a0, 16); a0 += __shfl_xor(a0, 32);
  a1 += __shfl_xor(a1, 16); a1 += __shfl_xor(a1, 32);
  a2 += __shfl_xor(a2, 16); a2 += __shfl_xor(a2, 32);
  a3 += __shfl_xor(a3, 16); a3 += __shfl_xor(a3, 32);
  a4 += __shfl_xor(a4, 16); a4 += __shfl_xor(a4, 32);
  a5 += __shfl_xor(a5, 16); a5 += __shfl_xor(a5, 32);
  a6 += __shfl_xor(a6, 16); a6 += __shfl_xor(a6, 32);
  a7 += __shfl_xor(a7, 16); a7 += __shfl_xor(a7, 32);

  float inv = (den > 0.f) ? 1.0f / den : 0.f;
  if (qt == 0) {
    uint4 o;
    o.x = (uint)f2b(a0 * inv) | ((uint)f2b(a1 * inv) << 16);
    o.y = (uint)f2b(a2 * inv) | ((uint)f2b(a3 * inv) << 16);
    o.z = (uint)f2b(a4 * inv) | ((uint)f2b(a5 * inv) << 16);
    o.w = (uint)f2b(a6 * inv) | ((uint)f2b(a7 * inv) << 16);
    *(uint4*)((char*)aggbf + (size_t)n * 256 + lb) = o;
  }
}

// ---------------- launch ----------------
extern "C" void kernel_launch(void* const* d_in, const int* in_sizes, int n_in,
                              void* d_out, int out_size, void* d_ws, size_t ws_size,
                              hipStream_t stream) {
  const float* h    = (const float*)d_in[0];
  const int*   src  = (const int*)d_in[1];
  const int*   dst  = (const int*)d_in[2];
  const float* Wq   = (const float*)d_in[3];
  const float* bq   = (const float*)d_in[4];
  const float* Wk   = (const float*)d_in[5];
  const float* bk   = (const float*)d_in[6];
  const float* Wm   = (const float*)d_in[7];
  const float* bm   = (const float*)d_in[8];
  const float* Wout = (const float*)d_in[9];
  const float* bout = (const float*)d_in[10];
  float* out = (float*)d_out;

  char* base = (char*)d_ws;
  ushort* Abf    = (ushort*)base;                         // NN*128 bf16 (reused as Zkm)
  char*   Zkm    = base;                                  // NN*256B int8, overlaps Abf
  ushort* Zbf    = (ushort*)(base + 25600000);            // NN*384 bf16
  ushort* aggbf  = (ushort*)(base + 102400000);           // NN*128 bf16
  float2* scales = (float2*)(base + 128000000);           // NN float2
  ushort* BTproj = (ushort*)(base + 128800000);           // 98304 B
  ushort* BTout  = (ushort*)(base + 128898304);           // 32768 B
  float*  bvec   = (float*)(base + 128931072);            // pad to 2048 B
  int* counts    = (int*)(base + 128933120);              // 400000 B
  int* offsets   = (int*)(base + 129333120);              // (NN+2)*4
  int* cursor    = (int*)(base + 129733128);              // 400000 B
  int* blockSums = (int*)(base + 130133128);              // 512 B
  int* csr_src   = (int*)(base + 130133640);              // NE*4

  hipMemsetAsync(counts, 0, (size_t)NN * sizeof(int), stream);

  setup_hist<<<12756, 256, 0, stream>>>(h, Abf, Wq, Wk, Wm, bq, bk, bm, Wout,
                                        BTproj, BTout, bvec, dst, counts);
  scan_a<<<98, 256, 0, stream>>>(counts, offsets, blockSums, NN);
  scan_b<<<1, 128, 0, stream>>>(blockSums, 98);
  scan_c<<<391, 256, 0, stream>>>(offsets, blockSums, cursor, NN);

  mfma_gemm<0, 1><<<dim3(782, 3), 256, 0, stream>>>(Abf, BTproj, bvec, Zbf, NN, 384);

  scatter_conv<<<9378, 256, 0, stream>>>(src, dst, cursor, csr_src, Zbf, Zkm, scales);

  aggregate_q<<<25000, 256, 0, stream>>>(Zkm, Zbf, scales, offsets, csr_src, aggbf);

  mfma_gemm<1, 0><<<dim3(782, 1), 256, 0, stream>>>(aggbf, BTout, bout, out, NN, 128);
}

// Round 11
// 338.558 us; speedup vs baseline: 1.3032x; 1.0105x over previous
//
#include <hip/hip_runtime.h>
#include <hip/hip_bf16.h>
#include <cstdint>
#include <cstddef>

#define NN 100000
#define NE 1600000
#define TAU 0.3f

typedef __attribute__((ext_vector_type(8))) short bf16x8;
typedef __attribute__((ext_vector_type(4))) float f32x4;

static __device__ __forceinline__ float b2f_hi(uint w) {
  return __uint_as_float(w & 0xffff0000u);
}
static __device__ __forceinline__ float b2f_lo(uint w) {
  return __uint_as_float(w << 16);
}
static __device__ __forceinline__ ushort f2b(float f) {
  uint x = __float_as_uint(f);
  return (ushort)((x + 0x7fffu + ((x >> 16) & 1u)) >> 16);
}
// sign-extended byte k of word w -> float
static __device__ __forceinline__ float i8f(uint w, int k) {
  return (float)((int)(w << (24 - 8 * k)) >> 24);
}

// ------- K1: hist (blocks 0..6249) + conv_h (6250..12499) + prep (12500..12755) -------
__global__ __launch_bounds__(256) void setup_hist(
    const float* __restrict__ h, ushort* __restrict__ A,
    const float* __restrict__ Wq, const float* __restrict__ Wk, const float* __restrict__ Wm,
    const float* __restrict__ bq, const float* __restrict__ bk, const float* __restrict__ bm,
    const float* __restrict__ Wout,
    ushort* __restrict__ BTproj, ushort* __restrict__ BTout, float* __restrict__ bvec,
    const int* __restrict__ dst, int* __restrict__ counts) {
  int b = blockIdx.x;
  if (b < 6250) {                       // histogram over dst
    int e = b * 256 + threadIdx.x;
    if (e < NE) atomicAdd(&counts[dst[e]], 1);
    return;
  }
  if (b < 12500) {                      // h f32 -> bf16
    int i = (b - 6250) * 256 + threadIdx.x;
    const float4* hv = (const float4*)h + (size_t)i * 2;
    float4 a = hv[0], c = hv[1];
    uint4 o;
    o.x = (uint)f2b(a.x) | ((uint)f2b(a.y) << 16);
    o.y = (uint)f2b(a.z) | ((uint)f2b(a.w) << 16);
    o.z = (uint)f2b(c.x) | ((uint)f2b(c.y) << 16);
    o.w = (uint)f2b(c.z) | ((uint)f2b(c.w) << 16);
    ((uint4*)A)[i] = o;
    return;
  }
  int id = (b - 12500) * 256 + threadIdx.x;   // weight prep, 65536 threads
  if (id < 384 * 128) {
    int j = id >> 7, k = id & 127;
    int w = j >> 7, r = j & 127, hh = r >> 5, d = r & 31;
    const float* W = (w == 0) ? Wq : (w == 1) ? Wk : Wm;
    BTproj[id] = f2b(W[hh * 4096 + k * 32 + d]);
    if (k == 0) {
      const float* bb = (w == 0) ? bq : (w == 1) ? bk : bm;
      bvec[j] = bb[hh * 32 + d];
    }
  } else {
    int id2 = id - 384 * 128;                // 16384
    int c = id2 >> 7, k = id2 & 127;
    BTout[id2] = f2b(Wout[k * 128 + c]);
  }
}

// ---------------- MFMA GEMM: C[M][ncols] = A[M][128] * BT^T + bias ----------------
template <int RELU, int OUTBF>
__global__ __launch_bounds__(256) void mfma_gemm(
    const ushort* __restrict__ A, const ushort* __restrict__ BT,
    const float* __restrict__ bias, void* __restrict__ Cp, int M, int ncols) {
  __shared__ ushort As[128 * 128];
  __shared__ ushort Bs[128 * 128];

  int t = threadIdx.x;
  int rowBase = blockIdx.x * 128, colBase = blockIdx.y * 128;

#pragma unroll
  for (int i = 0; i < 8; i++) {
    int flat = t + i * 256;
    int row = flat >> 4;
    int kb = (flat & 15) * 16;
    int soff = kb ^ ((row & 7) << 4);
    int ar = rowBase + row; if (ar >= M) ar = M - 1;
    __builtin_amdgcn_global_load_lds(
        (const __attribute__((address_space(1))) uint32_t*)((const char*)A + (size_t)ar * 256 + soff),
        (__attribute__((address_space(3))) uint32_t*)((char*)As + row * 256 + kb), 16, 0, 0);
    __builtin_amdgcn_global_load_lds(
        (const __attribute__((address_space(1))) uint32_t*)((const char*)BT + (size_t)(colBase + row) * 256 + soff),
        (__attribute__((address_space(3))) uint32_t*)((char*)Bs + row * 256 + kb), 16, 0, 0);
  }
  __syncthreads();

  int wv = t >> 6, L = t & 63;
  int wrow = (wv >> 1) * 64, wcol = (wv & 1) * 64;
  int lr = L & 15;
  int lk = (L >> 4) * 16;
  f32x4 acc[4][4] = {};

#pragma unroll
  for (int ks = 0; ks < 4; ks++) {
    bf16x8 a[4], b[4];
#pragma unroll
    for (int i = 0; i < 4; i++) {
      int row = wrow + i * 16 + lr;
      a[i] = *(const bf16x8*)((const char*)As + row * 256 + ((ks * 64 + lk) ^ ((row & 7) << 4)));
      int col = wcol + i * 16 + lr;
      b[i] = *(const bf16x8*)((const char*)Bs + col * 256 + ((ks * 64 + lk) ^ ((col & 7) << 4)));
    }
#pragma unroll
    for (int i = 0; i < 4; i++)
#pragma unroll
      for (int j = 0; j < 4; j++)
        acc[i][j] = __builtin_amdgcn_mfma_f32_16x16x32_bf16(a[i], b[j], acc[i][j], 0, 0, 0);
  }

  int rquad = (L >> 4) * 4;
#pragma unroll
  for (int j = 0; j < 4; j++) {
    int col = colBase + wcol + j * 16 + lr;
    float bs = bias[col];
#pragma unroll
    for (int i = 0; i < 4; i++) {
      int row0 = rowBase + wrow + i * 16 + rquad;
#pragma unroll
      for (int r = 0; r < 4; r++) {
        int row = row0 + r;
        if (row >= M) continue;
        float v = acc[i][j][r] + bs;
        if (RELU) v = fmaxf(v, 0.f);
        if (OUTBF) ((ushort*)Cp)[(size_t)row * ncols + col] = f2b(v);
        else       ((float*)Cp)[(size_t)row * ncols + col] = v;
      }
    }
  }
}

// ---------------- CSR scans ----------------
__global__ __launch_bounds__(256) void scan_a(const int* __restrict__ counts,
                                              int* __restrict__ offsets,
                                              int* __restrict__ blockSums, int n) {
  __shared__ int lds[256];
  int b = blockIdx.x, t = threadIdx.x;
  int base = b * 1024 + t * 4;
  int4 v = make_int4(0, 0, 0, 0);
  if (base < n) v = *(const int4*)&counts[base];
  int s1 = v.x + v.y, s2 = s1 + v.z, s3 = s2 + v.w;
  lds[t] = s3;
  __syncthreads();
  for (int dd = 1; dd < 256; dd <<= 1) {
    int x = (t >= dd) ? lds[t - dd] : 0;
    __syncthreads();
    lds[t] += x;
    __syncthreads();
  }
  int excl = (t > 0) ? lds[t - 1] : 0;
  if (base < n) {
    int4 o = make_int4(excl, excl + v.x, excl + s1, excl + s2);
    *(int4*)&offsets[base] = o;
  }
  if (t == 255) blockSums[b] = lds[255];
}

__global__ __launch_bounds__(128) void scan_b(int* __restrict__ blockSums, int nb) {
  __shared__ int lds[128];
  int t = threadIdx.x;
  lds[t] = (t < nb) ? blockSums[t] : 0;
  __syncthreads();
  for (int dd = 1; dd < 128; dd <<= 1) {
    int x = (t >= dd) ? lds[t - dd] : 0;
    __syncthreads();
    lds[t] += x;
    __syncthreads();
  }
  if (t < nb) blockSums[t] = (t > 0) ? lds[t - 1] : 0;
}

__global__ __launch_bounds__(256) void scan_c(int* __restrict__ offsets,
                                              const int* __restrict__ blockSums,
                                              int* __restrict__ cursor,
                                              int* __restrict__ partStart,
                                              int* __restrict__ stageCur, int n) {
  int i = blockIdx.x * 256 + threadIdx.x;
  if (i < n) {
    int v = offsets[i] + blockSums[i >> 10];
    offsets[i] = v;
    cursor[i] = v;
    if ((i & 16383) == 0) {            // partition starts: p = i>>14, p in 0..6
      partStart[i >> 14] = v;
      stageCur[i >> 14] = v;
    }
  }
  if (i == 0) {
    offsets[n] = NE;
    partStart[7] = NE; partStart[8] = NE;
    stageCur[7] = NE;
  }
}

// ------- Phase 1: stage edges by partition (blocks 0..781) + bf16->int8 quant (782..7031) ----
// Stage: each block bins its 2048-edge chunk into 8 dst-partitions (dst>>14), reserves
// contiguous slots with one global atomicAdd per partition, writes (src,dst) pairs densely.
__global__ __launch_bounds__(256) void stage_conv(
    const int* __restrict__ src, const int* __restrict__ dst,
    int* __restrict__ stageCur, int2* __restrict__ stage,
    const ushort* __restrict__ Zbf, char* __restrict__ Zkm,
    float2* __restrict__ scales) {
  int b = blockIdx.x;
  int t = threadIdx.x;
  if (b < 782) {
    __shared__ int cnt[8];
    __shared__ int gbase[8];
    if (t < 8) cnt[t] = 0;
    __syncthreads();
    int e0 = b * 2048 + t;
    int d[8], s[8];
#pragma unroll
    for (int i = 0; i < 8; i++) {
      int e = e0 + i * 256;
      if (e < NE) {
        d[i] = dst[e];
        s[i] = src[e];
        atomicAdd(&cnt[d[i] >> 14], 1);
      } else {
        d[i] = -1;
      }
    }
    __syncthreads();
    if (t < 8) gbase[t] = atomicAdd(&stageCur[t], cnt[t]);
    __syncthreads();
    if (t < 8) cnt[t] = 0;
    __syncthreads();
#pragma unroll
    for (int i = 0; i < 8; i++) {
      if (d[i] >= 0) {
        int p = d[i] >> 14;
        int slot = gbase[p] + atomicAdd(&cnt[p], 1);
        stage[slot] = make_int2(s[i], d[i]);
      }
    }
    return;
  }
  // quant branch: 6250 blocks = 1.6M threads = 100K rows x 16 units
  int g = (b - 782) * 256 + t;
  int row = g >> 4, u = g & 15;
  const ushort* zr = Zbf + (size_t)row * 384;
  uint4 kk = *(const uint4*)(zr + 128 + u * 8);
  uint4 mm = *(const uint4*)(zr + 256 + u * 8);
  float kf[8] = {b2f_lo(kk.x), b2f_hi(kk.x), b2f_lo(kk.y), b2f_hi(kk.y),
                 b2f_lo(kk.z), b2f_hi(kk.z), b2f_lo(kk.w), b2f_hi(kk.w)};
  float mf[8] = {b2f_lo(mm.x), b2f_hi(mm.x), b2f_lo(mm.y), b2f_hi(mm.y),
                 b2f_lo(mm.z), b2f_hi(mm.z), b2f_lo(mm.w), b2f_hi(mm.w)};
  float mk = 0.f, mx = 0.f;
#pragma unroll
  for (int i = 0; i < 8; i++) { mk = fmaxf(mk, fabsf(kf[i])); mx = fmaxf(mx, fabsf(mf[i])); }
#pragma unroll
  for (int dd = 1; dd < 16; dd <<= 1) {
    mk = fmaxf(mk, __shfl_xor(mk, dd));
    mx = fmaxf(mx, __shfl_xor(mx, dd));
  }
  mk = fmaxf(mk, 1e-20f); mx = fmaxf(mx, 1e-20f);
  float qk = 127.0f / mk, qm = 127.0f / mx;
  int q[16];
#pragma unroll
  for (int i = 0; i < 8; i++) {
    q[i] = __float2int_rn(kf[i] * qk) & 0xff;
    q[8 + i] = __float2int_rn(mf[i] * qm) & 0xff;
  }
  uint4 o;
  o.x = (uint)(q[0] | (q[1] << 8) | (q[2] << 16) | (q[3] << 24));
  o.y = (uint)(q[4] | (q[5] << 8) | (q[6] << 16) | (q[7] << 24));
  o.z = (uint)(q[8] | (q[9] << 8) | (q[10] << 16) | (q[11] << 24));
  o.w = (uint)(q[12] | (q[13] << 8) | (q[14] << 16) | (q[15] << 24));
  *(uint4*)(Zkm + (size_t)row * 256 + u * 16) = o;
  if (u == 0) scales[row] = make_float2(mk * (1.0f / 127.0f), mx * (1.0f / 127.0f));
}

// ------- Phase 2: per-partition scatter from stage into CSR (partition p = blockIdx&7) -----
// All blocks of one partition scatter into its ~1MB CSR slice; dirty:stream ~1:2 in one L2.
__global__ __launch_bounds__(256) void scatter_final(
    const int2* __restrict__ stage, const int* __restrict__ partStart,
    int* __restrict__ cursor, int* __restrict__ csr_src) {
  int p = blockIdx.x & 7;
  int k = blockIdx.x >> 3;
  int start = partStart[p], end = partStart[p + 1];
  int base = start + k * 2048 + threadIdx.x;
#pragma unroll
  for (int i = 0; i < 8; i++) {
    int idx = base + i * 256;
    if (idx < end) {
      int2 e = stage[idx];
      int pos = atomicAdd(&cursor[e.y], 1);
      csr_src[pos] = e.x;
    }
  }
}

// ---------------- fused attention + aggregation, int8 gathers (round-7 form) ----------------
__global__ __launch_bounds__(256) void aggregate_q(
    const char* __restrict__ Zkm, const ushort* __restrict__ Zbf,
    const float2* __restrict__ scales,
    const int* __restrict__ offsets, const int* __restrict__ csr_src,
    ushort* __restrict__ aggbf) {
  int wv = threadIdx.x >> 6, L = threadIdx.x & 63;
  int n = blockIdx.x * 4 + wv;
  if (n >= NN) return;
  int qt = L >> 4, l = L & 15;
  int lb = l << 4;                         // byte offset within 256B row

  uint4 qw = *(const uint4*)((const char*)Zbf + (size_t)n * 768 + lb);  // zq dims 8l..8l+7
  float q0 = b2f_lo(qw.x), q1 = b2f_hi(qw.x), q2 = b2f_lo(qw.y), q3 = b2f_hi(qw.y);
  float q4 = b2f_lo(qw.z), q5 = b2f_hi(qw.z), q6 = b2f_lo(qw.w), q7 = b2f_hi(qw.w);

  int start = offsets[n], end = offsets[n + 1];
  float den = 0.f;
  float a0 = 0.f, a1 = 0.f, a2 = 0.f, a3 = 0.f, a4 = 0.f, a5 = 0.f, a6 = 0.f, a7 = 0.f;
  int p = start;

  for (; p + 8 <= end; p += 8) {
    int s0 = csr_src[p + qt];
    int s1 = csr_src[p + 4 + qt];
    uint4 v0 = *(const uint4*)(Zkm + ((size_t)s0 << 8) + lb);
    uint4 v1 = *(const uint4*)(Zkm + ((size_t)s1 << 8) + lb);
    float2 sc0 = scales[s0];
    float2 sc1 = scales[s1];

    float pd0 = i8f(v0.x, 0) * q0;
    pd0 = fmaf(i8f(v0.x, 1), q1, pd0); pd0 = fmaf(i8f(v0.x, 2), q2, pd0);
    pd0 = fmaf(i8f(v0.x, 3), q3, pd0); pd0 = fmaf(i8f(v0.y, 0), q4, pd0);
    pd0 = fmaf(i8f(v0.y, 1), q5, pd0); pd0 = fmaf(i8f(v0.y, 2), q6, pd0);
    pd0 = fmaf(i8f(v0.y, 3), q7, pd0);
    float pd1 = i8f(v1.x, 0) * q0;
    pd1 = fmaf(i8f(v1.x, 1), q1, pd1); pd1 = fmaf(i8f(v1.x, 2), q2, pd1);
    pd1 = fmaf(i8f(v1.x, 3), q3, pd1); pd1 = fmaf(i8f(v1.y, 0), q4, pd1);
    pd1 = fmaf(i8f(v1.y, 1), q5, pd1); pd1 = fmaf(i8f(v1.y, 2), q6, pd1);
    pd1 = fmaf(i8f(v1.y, 3), q7, pd1);

    pd0 += __shfl_xor(pd0, 1); pd1 += __shfl_xor(pd1, 1);
    pd0 += __shfl_xor(pd0, 2); pd1 += __shfl_xor(pd1, 2);
    float w0 = __expf(TAU * sc0.x * pd0);
    float w1 = __expf(TAU * sc1.x * pd1);
    den += w0 + w1;
    float wm0 = w0 * sc0.y, wm1 = w1 * sc1.y;

    a0 = fmaf(i8f(v0.z, 0), wm0, a0); a1 = fmaf(i8f(v0.z, 1), wm0, a1);
    a2 = fmaf(i8f(v0.z, 2), wm0, a2); a3 = fmaf(i8f(v0.z, 3), wm0, a3);
    a4 = fmaf(i8f(v0.w, 0), wm0, a4); a5 = fmaf(i8f(v0.w, 1), wm0, a5);
    a6 = fmaf(i8f(v0.w, 2), wm0, a6); a7 = fmaf(i8f(v0.w, 3), wm0, a7);
    a0 = fmaf(i8f(v1.z, 0), wm1, a0); a1 = fmaf(i8f(v1.z, 1), wm1, a1);
    a2 = fmaf(i8f(v1.z, 2), wm1, a2); a3 = fmaf(i8f(v1.z, 3), wm1, a3);
    a4 = fmaf(i8f(v1.w, 0), wm1, a4); a5 = fmaf(i8f(v1.w, 1), wm1, a5);
    a6 = fmaf(i8f(v1.w, 2), wm1, a6); a7 = fmaf(i8f(v1.w, 3), wm1, a7);
  }

  for (; p < end; p += 4) {               // masked tail, whole wave stays
    int e = p + qt;
    int idx = (e < end) ? e : (end - 1);
    int s0 = csr_src[idx];
    uint4 v = *(const uint4*)(Zkm + ((size_t)s0 << 8) + lb);
    float2 sc = scales[s0];
    float pd = i8f(v.x, 0) * q0;
    pd = fmaf(i8f(v.x, 1), q1, pd); pd = fmaf(i8f(v.x, 2), q2, pd);
    pd = fmaf(i8f(v.x, 3), q3, pd); pd = fmaf(i8f(v.y, 0), q4, pd);
    pd = fmaf(i8f(v.y, 1), q5, pd); pd = fmaf(i8f(v.y, 2), q6, pd);
    pd = fmaf(i8f(v.y, 3), q7, pd);
    pd += __shfl_xor(pd, 1);
    pd += __shfl_xor(pd, 2);
    float w = (e < end) ? __expf(TAU * sc.x * pd) : 0.f;
    den += w;
    float wm = w * sc.y;
    a0 = fmaf(i8f(v.z, 0), wm, a0); a1 = fmaf(i8f(v.z, 1), wm, a1);
    a2 = fmaf(i8f(v.z, 2), wm, a2); a3 = fmaf(i8f(v.z, 3), wm, a3);
    a4 = fmaf(i8f(v.w, 0), wm, a4); a5 = fmaf(i8f(v.w, 1), wm, a5);
    a6 = fmaf(i8f(v.w, 2), wm, a6); a7 = fmaf(i8f(v.w, 3), wm, a7);
  }

  // combine the four quarters (same l -> same dims/head)
  den += __shfl_xor(den, 16); den += __shfl_xor(den, 32);
  a0 += __shfl_xor(a0, 16); a0 += __shfl_xor(a0, 32);
  a1 += __shfl_xor(a1, 16); a1 += __shfl_xor(a1, 32);
  a2 += __shfl_xor(a2, 16); a2 += __shfl_xor(a2, 32);
  a3 += __shfl_xor(a3, 16); a3 += __shfl_xor(a3, 32);
  a4 += __shfl_xor(a4, 16); a4 += __shfl_xor(a4, 32);
  a5 += __shfl_xor(a5, 16); a5 += __shfl_xor(a5, 32);
  a6 += __shfl_xor(a6, 16); a6 += __shfl_xor(a6, 32);
  a7 += __shfl_xor(a7, 16); a7 += __shfl_xor(a7, 32);

  float inv = (den > 0.f) ? 1.0f / den : 0.f;
  if (qt == 0) {
    uint4 o;
    o.x = (uint)f2b(a0 * inv) | ((uint)f2b(a1 * inv) << 16);
    o.y = (uint)f2b(a2 * inv) | ((uint)f2b(a3 * inv) << 16);
    o.z = (uint)f2b(a4 * inv) | ((uint)f2b(a5 * inv) << 16);
    o.w = (uint)f2b(a6 * inv) | ((uint)f2b(a7 * inv) << 16);
    *(uint4*)((char*)aggbf + (size_t)n * 256 + lb) = o;
  }
}

// ---------------- launch ----------------
extern "C" void kernel_launch(void* const* d_in, const int* in_sizes, int n_in,
                              void* d_out, int out_size, void* d_ws, size_t ws_size,
                              hipStream_t stream) {
  const float* h    = (const float*)d_in[0];
  const int*   src  = (const int*)d_in[1];
  const int*   dst  = (const int*)d_in[2];
  const float* Wq   = (const float*)d_in[3];
  const float* bq   = (const float*)d_in[4];
  const float* Wk   = (const float*)d_in[5];
  const float* bk   = (const float*)d_in[6];
  const float* Wm   = (const float*)d_in[7];
  const float* bm   = (const float*)d_in[8];
  const float* Wout = (const float*)d_in[9];
  const float* bout = (const float*)d_in[10];
  float* out = (float*)d_out;

  char* base = (char*)d_ws;
  ushort* Abf    = (ushort*)base;                         // NN*128 bf16 (reused as Zkm)
  char*   Zkm    = base;                                  // NN*256B int8, overlaps Abf
  ushort* Zbf    = (ushort*)(base + 25600000);            // NN*384 bf16
  ushort* aggbf  = (ushort*)(base + 102400000);           // NN*128 bf16
  int2*   stage  = (int2*)(base + 102400000);             // NE int2 (12.8MB), dead before aggbf written
  float2* scales = (float2*)(base + 128000000);           // NN float2
  ushort* BTproj = (ushort*)(base + 128800000);           // 98304 B
  ushort* BTout  = (ushort*)(base + 128898304);           // 32768 B
  float*  bvec   = (float*)(base + 128931072);            // pad to 2048 B
  int* counts    = (int*)(base + 128933120);              // 400000 B
  int* offsets   = (int*)(base + 129333120);              // (NN+2)*4
  int* cursor    = (int*)(base + 129733128);              // 400000 B
  int* blockSums = (int*)(base + 130133128);              // 512 B
  int* partStart = (int*)(base + 130133640);              // 9 ints
  int* stageCur  = (int*)(base + 130133676);              // 8 ints (pad to 130133760)
  int* csr_src   = (int*)(base + 130133760);              // NE*4

  hipMemsetAsync(counts, 0, (size_t)NN * sizeof(int), stream);

  setup_hist<<<12756, 256, 0, stream>>>(h, Abf, Wq, Wk, Wm, bq, bk, bm, Wout,
                                        BTproj, BTout, bvec, dst, counts);
  scan_a<<<98, 256, 0, stream>>>(counts, offsets, blockSums, NN);
  scan_b<<<1, 128, 0, stream>>>(blockSums, 98);
  scan_c<<<391, 256, 0, stream>>>(offsets, blockSums, cursor, partStart, stageCur, NN);

  mfma_gemm<0, 1><<<dim3(782, 3), 256, 0, stream>>>(Abf, BTproj, bvec, Zbf, NN, 384);

  stage_conv<<<7032, 256, 0, stream>>>(src, dst, stageCur, stage, Zbf, Zkm, scales);
  scatter_final<<<1040, 256, 0, stream>>>(stage, partStart, cursor, csr_src);

  aggregate_q<<<25000, 256, 0, stream>>>(Zkm, Zbf, scales, offsets, csr_src, aggbf);

  mfma_gemm<1, 0><<<dim3(782, 1), 256, 0, stream>>>(aggbf, BTout, bout, out, NN, 128);
}